// Round 1
// baseline (94618.164 us; speedup 1.0000x reference)
//
#include <hip/hip_runtime.h>

#define HH 128      // hidden size
#define G4 512      // 4*HH gates
#define TT 102400   // sequence length
#define BBATCH 8    // batch

// ---------------- fast activations (fp32, ~1e-6 rel err, overflow-safe) ----
__device__ __forceinline__ float fast_rcp(float d) {
    float r = __builtin_amdgcn_rcpf(d);
    return r * (2.0f - d * r);   // one NR step -> ~full fp32 precision
}
__device__ __forceinline__ float sigmoid_f(float x) {
    x = fminf(fmaxf(x, -30.0f), 30.0f);
    return fast_rcp(1.0f + __expf(-x));
}
__device__ __forceinline__ float tanh_f(float x) {
    float ax = fminf(fabsf(x), 30.0f);
    float e  = __expf(-2.0f * ax);
    float t  = (1.0f - e) * fast_rcp(1.0f + e);
    return copysignf(t, x);
}

// 128-长 dot: weight row in VGPRs (32x float4), h broadcast from LDS
__device__ __forceinline__ float dot128(const float4* __restrict__ wr,
                                        const float4* __restrict__ h4) {
    float a0 = 0.f, a1 = 0.f, a2 = 0.f, a3 = 0.f;
#pragma unroll
    for (int k = 0; k < 32; ++k) {
        float4 hv = h4[k];
        a0 = fmaf(hv.x, wr[k].x, a0);
        a1 = fmaf(hv.y, wr[k].y, a1);
        a2 = fmaf(hv.z, wr[k].z, a2);
        a3 = fmaf(hv.w, wr[k].w, a3);
    }
    return (a0 + a1) + (a2 + a3);
}

// ---------------------------------------------------------------------------
// One pipeline slot: blocks 0..7  = stage A (layer0 chain, chunk c)
//                    blocks 8..15 = stage C (layer1 chain, chunk c-2)
//                    blocks 16..47= stage B (xp1 = Wih1@h1 GEMM, chunk c-1)
// No dependencies between stages inside one launch; stream order provides
// producer->consumer ordering across launches (kernel-boundary acq/rel).
// ---------------------------------------------------------------------------
__launch_bounds__(512, 2)
__global__ void lstm_slot_kernel(
    const float* __restrict__ x,
    const float* __restrict__ Wih0, const float* __restrict__ Whh0,
    const float* __restrict__ bih0, const float* __restrict__ bhh0,
    const float* __restrict__ Wih1, const float* __restrict__ Whh1,
    const float* __restrict__ bih1, const float* __restrict__ bhh1,
    float* __restrict__ h1s, float* __restrict__ c1s,
    float* __restrict__ h2s, float* __restrict__ c2s,
    double* __restrict__ pooled,
    float* __restrict__ h1ring,   // [2][B][chunkT][HH]
    float* __restrict__ xpring,   // [2][B][chunkT][G4]
    int c, int chunkT, int nchunks)
{
    __shared__ __align__(16) float h_s[HH];
    __shared__ float gates_s[G4];
    const int g = threadIdx.x;

    if (blockIdx.x < 8) {
        // ---------------- stage A: layer-0 recurrence, chunk c -------------
        if (c >= nchunks) return;
        const int b = blockIdx.x;
        float4 wr[32];
        const float4* wsrc = (const float4*)(Whh0 + (size_t)g * HH);
#pragma unroll
        for (int k = 0; k < 32; ++k) wr[k] = wsrc[k];
        const float wih  = Wih0[g];
        const float bias = bih0[g] + bhh0[g];
        const int   grp  = g >> 7;             // wave-uniform (64 | 128)
        float creg = 0.f;
        if (g < HH) { creg = c1s[b * HH + g]; h_s[g] = h1s[b * HH + g]; }
        float* ringp = h1ring + ((size_t)(c & 1) * BBATCH + b) * (size_t)chunkT * HH;
        const float* xb = x + (size_t)b * TT + (size_t)c * chunkT;
        float xnext = xb[0];
        __syncthreads();
        for (int tt = 0; tt < chunkT; ++tt) {
            float xt = xnext;
            if (tt + 1 < chunkT) xnext = xb[tt + 1];   // prefetch
            float pre = fmaf(xt, wih, bias) + dot128(wr, (const float4*)h_s);
            float act = (grp == 2) ? tanh_f(pre) : sigmoid_f(pre);
            gates_s[g] = act;
            __syncthreads();
            if (g < HH) {
                float i_ = gates_s[g],          f_ = gates_s[HH + g];
                float g_ = gates_s[2 * HH + g], o_ = gates_s[3 * HH + g];
                creg = fmaf(f_, creg, i_ * g_);
                float hn = o_ * tanh_f(creg);
                h_s[g] = hn;
                ringp[(size_t)tt * HH + g] = hn;
            }
            __syncthreads();
        }
        if (g < HH) { c1s[b * HH + g] = creg; h1s[b * HH + g] = h_s[g]; }

    } else if (blockIdx.x < 16) {
        // ---------------- stage C: layer-1 recurrence, chunk c-2 -----------
        const int cc = c - 2;
        if (cc < 0 || cc >= nchunks) return;
        const int b = blockIdx.x - 8;
        float4 wr[32];
        const float4* wsrc = (const float4*)(Whh1 + (size_t)g * HH);
#pragma unroll
        for (int k = 0; k < 32; ++k) wr[k] = wsrc[k];
        const int grp = g >> 7;
        float creg = 0.f;
        double pacc = 0.0;
        if (g < HH) { creg = c2s[b * HH + g]; h_s[g] = h2s[b * HH + g]; }
        const float* xpp = xpring + ((size_t)(cc & 1) * BBATCH + b) * (size_t)chunkT * G4;
        float xpnext = xpp[g];
        __syncthreads();
        for (int tt = 0; tt < chunkT; ++tt) {
            float xpc = xpnext;
            if (tt + 1 < chunkT) xpnext = xpp[(size_t)(tt + 1) * G4 + g];  // prefetch
            float pre = xpc + dot128(wr, (const float4*)h_s);
            float act = (grp == 2) ? tanh_f(pre) : sigmoid_f(pre);
            gates_s[g] = act;
            __syncthreads();
            if (g < HH) {
                float i_ = gates_s[g],          f_ = gates_s[HH + g];
                float g_ = gates_s[2 * HH + g], o_ = gates_s[3 * HH + g];
                creg = fmaf(f_, creg, i_ * g_);
                float hn = o_ * tanh_f(creg);
                h_s[g] = hn;
                pacc += (double)hn;
            }
            __syncthreads();
        }
        if (g < HH) {
            c2s[b * HH + g] = creg;
            h2s[b * HH + g] = h_s[g];
            pooled[b * HH + g] += pacc;
        }

    } else {
        // ---------------- stage B: xp1 = Wih1 @ h1 + bias, chunk c-1 -------
        const int bc = c - 1;
        if (bc < 0 || bc >= nchunks) return;
        const int ib = blockIdx.x - 16;     // 0..31
        const int bb = ib >> 2;             // batch
        const int sl = ib & 3;              // t-slice (stride 4)
        float4 wr[32];
        const float4* wsrc = (const float4*)(Wih1 + (size_t)g * HH);
#pragma unroll
        for (int k = 0; k < 32; ++k) wr[k] = wsrc[k];
        const float bias = bih1[g] + bhh1[g];
        const float* hrp = h1ring + ((size_t)(bc & 1) * BBATCH + bb) * (size_t)chunkT * HH;
        float* xpp = xpring + ((size_t)(bc & 1) * BBATCH + bb) * (size_t)chunkT * G4;
        for (int tt = sl; tt < chunkT; tt += 4) {
            if (g < HH) h_s[g] = hrp[(size_t)tt * HH + g];
            __syncthreads();
            float v = bias + dot128(wr, (const float4*)h_s);
            xpp[(size_t)tt * G4 + g] = v;
            __syncthreads();
        }
    }
}

// ---------------- head: mean-pool (done) -> FC+ReLU -> FC ------------------
__global__ void head_kernel(const double* __restrict__ pooled,
                            const float* __restrict__ fcW1, const float* __restrict__ fcb1,
                            const float* __restrict__ fcW2, const float* __restrict__ fcb2,
                            float* __restrict__ out)
{
    __shared__ float p_s[HH];
    __shared__ float hid_s[64];
    const int b = blockIdx.x, t = threadIdx.x;
    if (t < HH) p_s[t] = (float)(pooled[b * HH + t] * (1.0 / (double)TT));
    __syncthreads();
    if (t < 64) {
        float acc = fcb1[t];
#pragma unroll 8
        for (int k = 0; k < HH; ++k) acc = fmaf(p_s[k], fcW1[t * HH + k], acc);
        hid_s[t] = fmaxf(acc, 0.f);
    }
    __syncthreads();
    if (t < 11) {
        float acc = fcb2[t];
#pragma unroll
        for (int k = 0; k < 64; ++k) acc = fmaf(hid_s[k], fcW2[t * 64 + k], acc);
        out[b * 11 + t] = acc;
    }
}

// ---------------------------------------------------------------------------
extern "C" void kernel_launch(void* const* d_in, const int* in_sizes, int n_in,
                              void* d_out, int out_size, void* d_ws, size_t ws_size,
                              hipStream_t stream)
{
    const float* x    = (const float*)d_in[0];
    const float* Wih0 = (const float*)d_in[1];
    const float* Whh0 = (const float*)d_in[2];
    const float* bih0 = (const float*)d_in[3];
    const float* bhh0 = (const float*)d_in[4];
    const float* Wih1 = (const float*)d_in[5];
    const float* Whh1 = (const float*)d_in[6];
    const float* bih1 = (const float*)d_in[7];
    const float* bhh1 = (const float*)d_in[8];
    const float* fcW1 = (const float*)d_in[9];
    const float* fcb1 = (const float*)d_in[10];
    const float* fcW2 = (const float*)d_in[11];
    const float* fcb2 = (const float*)d_in[12];
    float* out = (float*)d_out;

    // ---- workspace layout ----
    char* wsp = (char*)d_ws;
    float*  h1s    = (float*) (wsp + 0);
    float*  c1s    = (float*) (wsp + 4096);
    float*  h2s    = (float*) (wsp + 8192);
    float*  c2s    = (float*) (wsp + 12288);
    double* pooled = (double*)(wsp + 16384);          // 8 KB
    const size_t STATE_BYTES = 24576;

    // chunk size: biggest candidate whose double-buffered rings fit in ws.
    // per-t ring bytes: h1 2*8*128*4 = 8192? no: 2*8*128*4 = 8 KB... computed:
    //   h1ring: 2*8*chunkT*128*4  ;  xpring: 2*8*chunkT*512*4  => 40960 B per t
    static const int cands[] = {3200, 1600, 800, 400, 200, 100, 50, 25};
    int chunkT = 25;
    for (int i = 0; i < 8; ++i) {
        size_t need = STATE_BYTES + (size_t)40960 * (size_t)cands[i];
        if (need <= ws_size) { chunkT = cands[i]; break; }
    }
    const int nchunks = TT / chunkT;

    float* h1ring = (float*)(wsp + STATE_BYTES);
    float* xpring = (float*)(wsp + STATE_BYTES + (size_t)2 * BBATCH * chunkT * HH * 4);

    // zero persistent state (h/c/pooled); ws is poisoned before every call
    hipMemsetAsync(d_ws, 0, STATE_BYTES, stream);

    // pipeline: slot c runs A(c) || B(c-1) || C(c-2)
    const int nslots = nchunks + 2;
    for (int c = 0; c < nslots; ++c) {
        lstm_slot_kernel<<<48, 512, 0, stream>>>(
            x, Wih0, Whh0, bih0, bhh0, Wih1, Whh1, bih1, bhh1,
            h1s, c1s, h2s, c2s, pooled, h1ring, xpring,
            c, chunkT, nchunks);
    }
    head_kernel<<<BBATCH, 128, 0, stream>>>(pooled, fcW1, fcb1, fcW2, fcb2, out);
}

// Round 2
// 86343.762 us; speedup vs baseline: 1.0958x; 1.0958x over previous
//
#include <hip/hip_runtime.h>

#define HH 128      // hidden size
#define G4 512      // 4*HH gates
#define TT 102400   // sequence length
#define BB 8        // batch
#define SEGP 36     // padded k-segment stride (floats): 32 data + 4 pad
#define HPAD 144    // 4 segments per h buffer (4*36 floats = 576 B, 16B-aligned)

// ---------------- fast activations (fp32, ~1e-7 rel err, saturate cleanly) --
__device__ __forceinline__ float fast_rcp(float d) {
    float r = __builtin_amdgcn_rcpf(d);
    return r * (2.0f - d * r);            // one NR step
}
__device__ __forceinline__ float sigmoid_f(float x) {
    return fast_rcp(1.0f + __expf(-x));   // exp(+inf)->inf -> rcp->0 : safe
}
__device__ __forceinline__ float tanh_f(float x) {
    return fmaf(2.0f, fast_rcp(1.0f + __expf(-2.0f * x)), -1.0f);
}

// quad-split dot: lane l of quad q covers k in [32l,32l+32) of 4 rows.
// w[m][r]: row m's k-chunk as 8 float4. hseg: &h_s[buf][l*SEGP] (16B aligned).
// Result: s[0..3] = full 128-long dots, identical in all 4 quad lanes.
__device__ __forceinline__ void quad_dot4(const float4 w[4][8],
                                          const float* __restrict__ hseg,
                                          float s[4]) {
    const float4* h4 = (const float4*)hseg;
    float4 a0 = {0,0,0,0}, a1 = {0,0,0,0}, a2 = {0,0,0,0}, a3 = {0,0,0,0};
#pragma unroll
    for (int r = 0; r < 8; ++r) {
        float4 hv = h4[r];                 // ds_read_b128, 4-group bank-clean
        a0.x = fmaf(hv.x, w[0][r].x, a0.x); a0.y = fmaf(hv.y, w[0][r].y, a0.y);
        a0.z = fmaf(hv.z, w[0][r].z, a0.z); a0.w = fmaf(hv.w, w[0][r].w, a0.w);
        a1.x = fmaf(hv.x, w[1][r].x, a1.x); a1.y = fmaf(hv.y, w[1][r].y, a1.y);
        a1.z = fmaf(hv.z, w[1][r].z, a1.z); a1.w = fmaf(hv.w, w[1][r].w, a1.w);
        a2.x = fmaf(hv.x, w[2][r].x, a2.x); a2.y = fmaf(hv.y, w[2][r].y, a2.y);
        a2.z = fmaf(hv.z, w[2][r].z, a2.z); a2.w = fmaf(hv.w, w[2][r].w, a2.w);
        a3.x = fmaf(hv.x, w[3][r].x, a3.x); a3.y = fmaf(hv.y, w[3][r].y, a3.y);
        a3.z = fmaf(hv.z, w[3][r].z, a3.z); a3.w = fmaf(hv.w, w[3][r].w, a3.w);
    }
    s[0] = (a0.x + a0.y) + (a0.z + a0.w);
    s[1] = (a1.x + a1.y) + (a1.z + a1.w);
    s[2] = (a2.x + a2.y) + (a2.z + a2.w);
    s[3] = (a3.x + a3.y) + (a3.z + a3.w);
    // intra-quad butterfly: bitwise-identical sums in all 4 lanes
#pragma unroll
    for (int m = 0; m < 4; ++m) {
        s[m] += __shfl_xor(s[m], 1, 64);
        s[m] += __shfl_xor(s[m], 2, 64);
    }
}

// load 4 gate-row k-chunks for this thread (rows q+128m, k from 32l)
__device__ __forceinline__ void load_w(const float* __restrict__ W,
                                       int q, int l, float4 w[4][8]) {
#pragma unroll
    for (int m = 0; m < 4; ++m) {
        const float4* rp = (const float4*)(W + (size_t)(q + 128 * m) * HH + 32 * l);
#pragma unroll
        for (int r = 0; r < 8; ++r) w[m][r] = rp[r];
    }
}

// ---------------------------------------------------------------------------
// One pipeline slot: blocks 0..7  = stage A (layer0 chain, chunk c)
//                    blocks 8..15 = stage C (layer1 chain, chunk c-2)
//                    blocks 16..79= stage B (xp1 = Wih1@h1 GEMM, chunk c-1)
// Stages are independent within a launch; stream order gives producer->
// consumer ordering across launches (kernel-boundary release/acquire).
// ---------------------------------------------------------------------------
__launch_bounds__(512, 2)
__global__ void lstm_slot_kernel(
    const float* __restrict__ x,
    const float* __restrict__ Wih0, const float* __restrict__ Whh0,
    const float* __restrict__ bih0, const float* __restrict__ bhh0,
    const float* __restrict__ Wih1, const float* __restrict__ Whh1,
    const float* __restrict__ bih1, const float* __restrict__ bhh1,
    float* __restrict__ h1s, float* __restrict__ c1s,
    float* __restrict__ h2s, float* __restrict__ c2s,
    double* __restrict__ pooled,
    float* __restrict__ h1ring,   // [2][B][chunkT][HH]
    float* __restrict__ xpring,   // [2][B][chunkT][G4]
    int c, int chunkT, int nchunks)
{
    __shared__ __align__(16) float h_s[2][HPAD];
    const int t = threadIdx.x;
    const int q = t >> 2;        // cell / output-column (0..127)
    const int l = t & 3;         // k-quarter lane

    if (blockIdx.x < 8) {
        // ---------------- stage A: layer-0 recurrence, chunk c -------------
        if (c >= nchunks) return;
        const int b = blockIdx.x;
        float4 w[4][8];
        load_w(Whh0, q, l, w);
        float bias4[4], wih4[4];
#pragma unroll
        for (int m = 0; m < 4; ++m) {
            int r = q + 128 * m;
            bias4[m] = bih0[r] + bhh0[r];
            wih4[m]  = Wih0[r];
        }
        float c_reg = c1s[b * HH + q];      // replicated per quad (identical)
        if (t < HH) h_s[0][(t >> 5) * SEGP + (t & 31)] = h1s[b * HH + t];
        float* ringp = h1ring + ((size_t)((c & 1) * BB + b)) * (size_t)chunkT * HH;
        const float* xb = x + (size_t)b * TT + (size_t)c * chunkT;
        float xcur = xb[0];
        float h = 0.f;
        int buf = 0;
        __syncthreads();
        for (int tt = 0; tt < chunkT; ++tt) {
            float xnext = (tt + 1 < chunkT) ? xb[tt + 1] : 0.f;
            float s[4];
            quad_dot4(w, &h_s[buf][l * SEGP], s);
            float pre0 = fmaf(xcur, wih4[0], s[0] + bias4[0]);
            float pre1 = fmaf(xcur, wih4[1], s[1] + bias4[1]);
            float pre2 = fmaf(xcur, wih4[2], s[2] + bias4[2]);
            float pre3 = fmaf(xcur, wih4[3], s[3] + bias4[3]);
            float i_ = sigmoid_f(pre0), f_ = sigmoid_f(pre1);
            float g_ = tanh_f(pre2),    o_ = sigmoid_f(pre3);
            c_reg = fmaf(f_, c_reg, i_ * g_);
            h = o_ * tanh_f(c_reg);
            int nb = buf ^ 1;
            if (l == 0) {
                h_s[nb][(q >> 5) * SEGP + (q & 31)] = h;
                ringp[(size_t)tt * HH + q] = h;
            }
            __syncthreads();                // h_s[nb] ready; old reads done
            buf = nb;
            xcur = xnext;
        }
        if (l == 0) { c1s[b * HH + q] = c_reg; h1s[b * HH + q] = h; }

    } else if (blockIdx.x < 16) {
        // ---------------- stage C: layer-1 recurrence, chunk c-2 -----------
        const int cc = c - 2;
        if (cc < 0 || cc >= nchunks) return;
        const int b = blockIdx.x - 8;
        float4 w[4][8];
        load_w(Whh1, q, l, w);
        float c_reg = c2s[b * HH + q];
        double pacc = 0.0;
        if (t < HH) h_s[0][(t >> 5) * SEGP + (t & 31)] = h2s[b * HH + t];
        const float* xpp = xpring + ((size_t)((cc & 1) * BB + b)) * (size_t)chunkT * G4;
        float xp4[4];
#pragma unroll
        for (int m = 0; m < 4; ++m) xp4[m] = xpp[q + 128 * m];   // bias folded by B
        float h = 0.f;
        int buf = 0;
        __syncthreads();
        for (int tt = 0; tt < chunkT; ++tt) {
            float xp4n[4] = {0.f, 0.f, 0.f, 0.f};
            if (tt + 1 < chunkT) {
#pragma unroll
                for (int m = 0; m < 4; ++m)
                    xp4n[m] = xpp[(size_t)(tt + 1) * G4 + q + 128 * m];
            }
            float s[4];
            quad_dot4(w, &h_s[buf][l * SEGP], s);
            float i_ = sigmoid_f(s[0] + xp4[0]), f_ = sigmoid_f(s[1] + xp4[1]);
            float g_ = tanh_f(s[2] + xp4[2]),    o_ = sigmoid_f(s[3] + xp4[3]);
            c_reg = fmaf(f_, c_reg, i_ * g_);
            h = o_ * tanh_f(c_reg);
            int nb = buf ^ 1;
            if (l == 0) {
                h_s[nb][(q >> 5) * SEGP + (q & 31)] = h;
                pacc += (double)h;
            }
            __syncthreads();
            buf = nb;
#pragma unroll
            for (int m = 0; m < 4; ++m) xp4[m] = xp4n[m];
        }
        if (l == 0) {
            c2s[b * HH + q] = c_reg;
            h2s[b * HH + q] = h;
            pooled[b * HH + q] += pacc;
        }

    } else {
        // ---------------- stage B: xp1 = Wih1 @ h1 + bias, chunk c-1 -------
        const int bc = c - 1;
        if (bc < 0 || bc >= nchunks) return;
        const int ib = blockIdx.x - 16;     // 0..63
        const int bb = ib >> 3;             // batch
        const int sl = ib & 7;              // t-slice (stride 8)
        float4 w[4][8];
        load_w(Wih1, q, l, w);
        float bias4[4];
#pragma unroll
        for (int m = 0; m < 4; ++m) {
            int r = q + 128 * m;
            bias4[m] = bih1[r] + bhh1[r];
        }
        const float* hrp = h1ring + ((size_t)((bc & 1) * BB + bb)) * (size_t)chunkT * HH;
        float* xpw = xpring + ((size_t)((bc & 1) * BB + bb)) * (size_t)chunkT * G4;
        // prologue: stage first h tile
        if (t < HH) h_s[0][(t >> 5) * SEGP + (t & 31)] = hrp[(size_t)sl * HH + t];
        __syncthreads();
        int p = 0;
        for (int tt = sl; tt < chunkT; tt += 8) {
            int ttn = tt + 8;
            bool pf = (t < HH) && (ttn < chunkT);
            float hn = 0.f;
            if (pf) hn = hrp[(size_t)ttn * HH + t];     // prefetch next tile
            float s[4];
            quad_dot4(w, &h_s[p][l * SEGP], s);
            float pre0 = s[0] + bias4[0], pre1 = s[1] + bias4[1];
            float pre2 = s[2] + bias4[2], pre3 = s[3] + bias4[3];
            if (pf) h_s[p ^ 1][(t >> 5) * SEGP + (t & 31)] = hn;
            float val = (l == 0) ? pre0 : (l == 1) ? pre1 : (l == 2) ? pre2 : pre3;
            xpw[(size_t)tt * G4 + q + 128 * l] = val;
            __syncthreads();
            p ^= 1;
        }
    }
}

// ---------------- head: mean-pool (done) -> FC+ReLU -> FC ------------------
__global__ void head_kernel(const double* __restrict__ pooled,
                            const float* __restrict__ fcW1, const float* __restrict__ fcb1,
                            const float* __restrict__ fcW2, const float* __restrict__ fcb2,
                            float* __restrict__ out)
{
    __shared__ float p_s[HH];
    __shared__ float hid_s[64];
    const int b = blockIdx.x, t = threadIdx.x;
    if (t < HH) p_s[t] = (float)(pooled[b * HH + t] * (1.0 / (double)TT));
    __syncthreads();
    if (t < 64) {
        float acc = fcb1[t];
#pragma unroll 8
        for (int k = 0; k < HH; ++k) acc = fmaf(p_s[k], fcW1[t * HH + k], acc);
        hid_s[t] = fmaxf(acc, 0.f);
    }
    __syncthreads();
    if (t < 11) {
        float acc = fcb2[t];
#pragma unroll
        for (int k = 0; k < 64; ++k) acc = fmaf(hid_s[k], fcW2[t * 64 + k], acc);
        out[b * 11 + t] = acc;
    }
}

// ---------------------------------------------------------------------------
extern "C" void kernel_launch(void* const* d_in, const int* in_sizes, int n_in,
                              void* d_out, int out_size, void* d_ws, size_t ws_size,
                              hipStream_t stream)
{
    const float* x    = (const float*)d_in[0];
    const float* Wih0 = (const float*)d_in[1];
    const float* Whh0 = (const float*)d_in[2];
    const float* bih0 = (const float*)d_in[3];
    const float* bhh0 = (const float*)d_in[4];
    const float* Wih1 = (const float*)d_in[5];
    const float* Whh1 = (const float*)d_in[6];
    const float* bih1 = (const float*)d_in[7];
    const float* bhh1 = (const float*)d_in[8];
    const float* fcW1 = (const float*)d_in[9];
    const float* fcb1 = (const float*)d_in[10];
    const float* fcW2 = (const float*)d_in[11];
    const float* fcb2 = (const float*)d_in[12];
    float* out = (float*)d_out;

    // ---- workspace layout ----
    char* wsp = (char*)d_ws;
    float*  h1s    = (float*) (wsp + 0);
    float*  c1s    = (float*) (wsp + 4096);
    float*  h2s    = (float*) (wsp + 8192);
    float*  c2s    = (float*) (wsp + 12288);
    double* pooled = (double*)(wsp + 16384);          // 8 KB
    const size_t STATE_BYTES = 24576;

    // chunk size: biggest candidate (multiple of 8, divides TT) whose
    // double-buffered rings fit: per-t bytes = 2*8*128*4 + 2*8*512*4 = 40960
    static const int cands[] = {3200, 1600, 800, 400, 160, 80, 40, 8};
    int chunkT = 8;
    for (int i = 0; i < 8; ++i) {
        size_t need = STATE_BYTES + (size_t)40960 * (size_t)cands[i];
        if (need <= ws_size) { chunkT = cands[i]; break; }
    }
    const int nchunks = TT / chunkT;

    float* h1ring = (float*)(wsp + STATE_BYTES);
    float* xpring = (float*)(wsp + STATE_BYTES + (size_t)2 * BB * chunkT * HH * 4);

    // zero persistent state (h/c/pooled); ws is re-poisoned before every call
    hipMemsetAsync(d_ws, 0, STATE_BYTES, stream);

    // pipeline: slot c runs A(c) || B(c-1) || C(c-2)
    const int nslots = nchunks + 2;
    for (int c = 0; c < nslots; ++c) {
        lstm_slot_kernel<<<80, 512, 0, stream>>>(
            x, Wih0, Whh0, bih0, bhh0, Wih1, Whh1, bih1, bhh1,
            h1s, c1s, h2s, c2s, pooled, h1ring, xpring,
            c, chunkT, nchunks);
    }
    head_kernel<<<BB, 128, 0, stream>>>(pooled, fcW1, fcb1, fcW2, fcb2, out);
}

// Round 3
// 69546.649 us; speedup vs baseline: 1.3605x; 1.2415x over previous
//
#include <hip/hip_runtime.h>

#define HH 128      // hidden size
#define G4 512      // 4*HH gates
#define TT 102400   // sequence length
#define BB 8        // batch
#define SEGP 36     // padded k-segment stride (floats): 32 data + 4 pad
#define HPAD 144    // 4 segments per h buffer

// ---------------- DPP quad butterfly (VALU pipe, not LDS!) -----------------
template<int CTRL>
__device__ __forceinline__ float dpp_add(float v) {
    int p = __builtin_amdgcn_update_dpp(0, __float_as_int(v), CTRL, 0xF, 0xF, true);
    return v + __int_as_float(p);
}
// xor1 = quad_perm[1,0,3,2] = 0xB1 ; xor2 = quad_perm[2,3,0,1] = 0x4E

// ---------------- fast activations (raw v_rcp = 1 ulp; saturate cleanly) ---
__device__ __forceinline__ float sig_f(float x) {
    return __builtin_amdgcn_rcpf(1.0f + __expf(-x));
}
__device__ __forceinline__ float tanh_f(float x) {
    return fmaf(2.0f, __builtin_amdgcn_rcpf(1.0f + __expf(-2.0f * x)), -1.0f);
}

// quad-split dot: lane l of quad q covers k in [32l,32l+32) of 4 gate rows.
// Result: s[0..3] full 128-long dots, identical in all 4 quad lanes (DPP).
__device__ __forceinline__ void quad_dot4(const float4 w[4][8],
                                          const float* __restrict__ hseg,
                                          float s[4]) {
    const float4* h4 = (const float4*)hseg;
    float4 a0 = {0,0,0,0}, a1 = {0,0,0,0}, a2 = {0,0,0,0}, a3 = {0,0,0,0};
#pragma unroll
    for (int r = 0; r < 8; ++r) {
        float4 hv = h4[r];                 // ds_read_b128, bank-clean
        a0.x = fmaf(hv.x, w[0][r].x, a0.x); a0.y = fmaf(hv.y, w[0][r].y, a0.y);
        a0.z = fmaf(hv.z, w[0][r].z, a0.z); a0.w = fmaf(hv.w, w[0][r].w, a0.w);
        a1.x = fmaf(hv.x, w[1][r].x, a1.x); a1.y = fmaf(hv.y, w[1][r].y, a1.y);
        a1.z = fmaf(hv.z, w[1][r].z, a1.z); a1.w = fmaf(hv.w, w[1][r].w, a1.w);
        a2.x = fmaf(hv.x, w[2][r].x, a2.x); a2.y = fmaf(hv.y, w[2][r].y, a2.y);
        a2.z = fmaf(hv.z, w[2][r].z, a2.z); a2.w = fmaf(hv.w, w[2][r].w, a2.w);
        a3.x = fmaf(hv.x, w[3][r].x, a3.x); a3.y = fmaf(hv.y, w[3][r].y, a3.y);
        a3.z = fmaf(hv.z, w[3][r].z, a3.z); a3.w = fmaf(hv.w, w[3][r].w, a3.w);
    }
    s[0] = (a0.x + a0.y) + (a0.z + a0.w);
    s[1] = (a1.x + a1.y) + (a1.z + a1.w);
    s[2] = (a2.x + a2.y) + (a2.z + a2.w);
    s[3] = (a3.x + a3.y) + (a3.z + a3.w);
#pragma unroll
    for (int m = 0; m < 4; ++m) {
        s[m] = dpp_add<0xB1>(s[m]);        // += lane^1 (quad_perm)
        s[m] = dpp_add<0x4E>(s[m]);        // += lane^2 (quad_perm)
    }
}

// load 4 gate-row k-chunks for this thread (rows q+128m, k from 32l)
__device__ __forceinline__ void load_w(const float* __restrict__ W,
                                       int q, int l, float4 w[4][8]) {
#pragma unroll
    for (int m = 0; m < 4; ++m) {
        const float4* rp = (const float4*)(W + (size_t)(q + 128 * m) * HH + 32 * l);
#pragma unroll
        for (int r = 0; r < 8; ++r) w[m][r] = rp[r];
    }
}

// ---------------------------------------------------------------------------
// One pipeline slot: blocks 0..7  = stage A (layer0 chain, chunk c)
//                    blocks 8..15 = stage C (layer1 chain, chunk c-2)
//                    blocks 16..79= stage B (xp1 = Wih1@h1 GEMM, chunk c-1)
// Stages independent within a launch; stream order gives producer->consumer
// ordering across launches (kernel-boundary release/acquire).
// ---------------------------------------------------------------------------
__launch_bounds__(512, 2)
__global__ void lstm_slot_kernel(
    const float* __restrict__ x,
    const float* __restrict__ Wih0, const float* __restrict__ Whh0,
    const float* __restrict__ bih0, const float* __restrict__ bhh0,
    const float* __restrict__ Wih1, const float* __restrict__ Whh1,
    const float* __restrict__ bih1, const float* __restrict__ bhh1,
    float* __restrict__ h1s, float* __restrict__ c1s,
    float* __restrict__ h2s, float* __restrict__ c2s,
    double* __restrict__ pooled,
    float* __restrict__ h1ring,   // [2][B][chunkT][HH]
    float* __restrict__ xpring,   // [2][B][chunkT][HH][4]  (t,q,gate)
    int c, int chunkT, int nchunks)
{
    __shared__ __align__(16) float h_s[2][HPAD];
    const int t = threadIdx.x;
    const int q = t >> 2;        // cell / output-column (0..127)
    const int l = t & 3;         // k-quarter lane
    const int seg_q = (q >> 5) * SEGP + (q & 31);

    if (blockIdx.x < 8) {
        // ---------------- stage A: layer-0 recurrence, chunk c -------------
        if (c >= nchunks) return;
        const int b = blockIdx.x;
        float4 w[4][8];
        load_w(Whh0, q, l, w);
        float bias4[4], wih4[4];
#pragma unroll
        for (int m = 0; m < 4; ++m) {
            int r = q + 128 * m;
            bias4[m] = bih0[r] + bhh0[r];
            wih4[m]  = Wih0[r];
        }
        float c_reg = c1s[b * HH + q];      // replicated per quad (identical)
        if (t < HH) h_s[0][(t >> 5) * SEGP + (t & 31)] = h1s[b * HH + t];
        float* ringp = h1ring + ((size_t)((c & 1) * BB + b)) * (size_t)chunkT * HH;
        const float4* xb4 = (const float4*)(x + (size_t)b * TT + (size_t)c * chunkT);
        const int nt4 = chunkT >> 2;
        float4 xq = xb4[0];
        float h = 0.f;
        __syncthreads();
        for (int t4 = 0; t4 < nt4; ++t4) {
            float4 xqn = {0, 0, 0, 0};
            if (t4 + 1 < nt4) xqn = xb4[t4 + 1];           // prefetch 4 steps
#pragma unroll
            for (int u = 0; u < 4; ++u) {
                const int buf = u & 1;                     // tt parity (static)
                float xt = (u == 0) ? xq.x : (u == 1) ? xq.y : (u == 2) ? xq.z : xq.w;
                float s[4];
                quad_dot4(w, &h_s[buf][l * SEGP], s);
                float i_ = sig_f (fmaf(xt, wih4[0], s[0] + bias4[0]));
                float f_ = sig_f (fmaf(xt, wih4[1], s[1] + bias4[1]));
                float g_ = tanh_f(fmaf(xt, wih4[2], s[2] + bias4[2]));
                float o_ = sig_f (fmaf(xt, wih4[3], s[3] + bias4[3]));
                c_reg = fmaf(f_, c_reg, i_ * g_);
                h = o_ * tanh_f(c_reg);
                if (l == 0) {
                    h_s[buf ^ 1][seg_q] = h;
                    ringp[(size_t)(t4 * 4 + u) * HH + q] = h;
                }
                __syncthreads();
            }
            xq = xqn;
        }
        if (l == 0) { c1s[b * HH + q] = c_reg; h1s[b * HH + q] = h; }

    } else if (blockIdx.x < 16) {
        // ---------------- stage C: layer-1 recurrence, chunk c-2 -----------
        const int cc = c - 2;
        if (cc < 0 || cc >= nchunks) return;
        const int b = blockIdx.x - 8;
        float4 w[4][8];
        load_w(Whh1, q, l, w);
        float c_reg = c2s[b * HH + q];
        double pacc = 0.0;
        if (t < HH) h_s[0][(t >> 5) * SEGP + (t & 31)] = h2s[b * HH + t];
        // xpring layout: [t][q][gate] -> float4 index t*HH + q (bias folded by B)
        const float4* xpq = (const float4*)(xpring
            + ((size_t)((cc & 1) * BB + b)) * (size_t)chunkT * G4);
        const int nt4 = chunkT >> 2;
        float4 xc[4];
#pragma unroll
        for (int u = 0; u < 4; ++u) xc[u] = xpq[(size_t)u * HH + q];
        float h = 0.f;
        __syncthreads();
        for (int t4 = 0; t4 < nt4; ++t4) {
            float4 xn[4] = {{0,0,0,0},{0,0,0,0},{0,0,0,0},{0,0,0,0}};
            if (t4 + 1 < nt4) {
#pragma unroll
                for (int u = 0; u < 4; ++u)
                    xn[u] = xpq[(size_t)(t4 * 4 + 4 + u) * HH + q];  // prefetch
            }
#pragma unroll
            for (int u = 0; u < 4; ++u) {
                const int buf = u & 1;
                float s[4];
                quad_dot4(w, &h_s[buf][l * SEGP], s);
                float i_ = sig_f (s[0] + xc[u].x);
                float f_ = sig_f (s[1] + xc[u].y);
                float g_ = tanh_f(s[2] + xc[u].z);
                float o_ = sig_f (s[3] + xc[u].w);
                c_reg = fmaf(f_, c_reg, i_ * g_);
                h = o_ * tanh_f(c_reg);
                if (l == 0) {
                    h_s[buf ^ 1][seg_q] = h;
                    pacc += (double)h;
                }
                __syncthreads();
            }
#pragma unroll
            for (int u = 0; u < 4; ++u) xc[u] = xn[u];
        }
        if (l == 0) {
            c2s[b * HH + q] = c_reg;
            h2s[b * HH + q] = h;
            pooled[b * HH + q] += pacc;
        }

    } else {
        // ---------------- stage B: xp1 = Wih1 @ h1 + bias, chunk c-1 -------
        const int bc = c - 1;
        if (bc < 0 || bc >= nchunks) return;
        const int ib = blockIdx.x - 16;     // 0..63
        const int bb = ib >> 3;             // batch
        const int sl = ib & 7;              // t-slice (stride 8)
        float4 w[4][8];
        load_w(Wih1, q, l, w);
        float bias4[4];
#pragma unroll
        for (int m = 0; m < 4; ++m) {
            int r = q + 128 * m;
            bias4[m] = bih1[r] + bhh1[r];
        }
        const float* hrp = h1ring + ((size_t)((bc & 1) * BB + bb)) * (size_t)chunkT * HH;
        float* xpw = xpring + ((size_t)((bc & 1) * BB + bb)) * (size_t)chunkT * G4;
        if (t < HH) h_s[0][(t >> 5) * SEGP + (t & 31)] = hrp[(size_t)sl * HH + t];
        __syncthreads();
        int p = 0;
        for (int tt = sl; tt < chunkT; tt += 8) {
            int ttn = tt + 8;
            bool pf = (t < HH) && (ttn < chunkT);
            float hn = 0.f;
            if (pf) hn = hrp[(size_t)ttn * HH + t];     // prefetch next tile
            float s[4];
            quad_dot4(w, &h_s[p][l * SEGP], s);
            if (pf) h_s[p ^ 1][(t >> 5) * SEGP + (t & 31)] = hn;
            float v0 = s[0] + bias4[0], v1 = s[1] + bias4[1];
            float v2 = s[2] + bias4[2], v3 = s[3] + bias4[3];
            // lane l writes gate l of row q: addr = tt*512 + q*4 + l = tt*512 + tid
            float val = (l == 0) ? v0 : (l == 1) ? v1 : (l == 2) ? v2 : v3;
            xpw[(size_t)tt * G4 + t] = val;
            __syncthreads();
            p ^= 1;
        }
    }
}

// ---------------- head: mean-pool (done) -> FC+ReLU -> FC ------------------
__global__ void head_kernel(const double* __restrict__ pooled,
                            const float* __restrict__ fcW1, const float* __restrict__ fcb1,
                            const float* __restrict__ fcW2, const float* __restrict__ fcb2,
                            float* __restrict__ out)
{
    __shared__ float p_s[HH];
    __shared__ float hid_s[64];
    const int b = blockIdx.x, t = threadIdx.x;
    if (t < HH) p_s[t] = (float)(pooled[b * HH + t] * (1.0 / (double)TT));
    __syncthreads();
    if (t < 64) {
        float acc = fcb1[t];
#pragma unroll 8
        for (int k = 0; k < HH; ++k) acc = fmaf(p_s[k], fcW1[t * HH + k], acc);
        hid_s[t] = fmaxf(acc, 0.f);
    }
    __syncthreads();
    if (t < 11) {
        float acc = fcb2[t];
#pragma unroll
        for (int k = 0; k < 64; ++k) acc = fmaf(hid_s[k], fcW2[t * 64 + k], acc);
        out[b * 11 + t] = acc;
    }
}

// ---------------------------------------------------------------------------
extern "C" void kernel_launch(void* const* d_in, const int* in_sizes, int n_in,
                              void* d_out, int out_size, void* d_ws, size_t ws_size,
                              hipStream_t stream)
{
    const float* x    = (const float*)d_in[0];
    const float* Wih0 = (const float*)d_in[1];
    const float* Whh0 = (const float*)d_in[2];
    const float* bih0 = (const float*)d_in[3];
    const float* bhh0 = (const float*)d_in[4];
    const float* Wih1 = (const float*)d_in[5];
    const float* Whh1 = (const float*)d_in[6];
    const float* bih1 = (const float*)d_in[7];
    const float* bhh1 = (const float*)d_in[8];
    const float* fcW1 = (const float*)d_in[9];
    const float* fcb1 = (const float*)d_in[10];
    const float* fcW2 = (const float*)d_in[11];
    const float* fcb2 = (const float*)d_in[12];
    float* out = (float*)d_out;

    // ---- workspace layout ----
    char* wsp = (char*)d_ws;
    float*  h1s    = (float*) (wsp + 0);
    float*  c1s    = (float*) (wsp + 4096);
    float*  h2s    = (float*) (wsp + 8192);
    float*  c2s    = (float*) (wsp + 12288);
    double* pooled = (double*)(wsp + 16384);          // 8 KB
    const size_t STATE_BYTES = 24576;

    // chunk size: biggest candidate (multiple of 8, divides TT) whose
    // double-buffered rings fit: per-t bytes = 2*8*128*4 + 2*8*512*4 = 40960
    static const int cands[] = {3200, 1600, 800, 400, 160, 80, 40, 8};
    int chunkT = 8;
    for (int i = 0; i < 8; ++i) {
        size_t need = STATE_BYTES + (size_t)40960 * (size_t)cands[i];
        if (need <= ws_size) { chunkT = cands[i]; break; }
    }
    const int nchunks = TT / chunkT;

    float* h1ring = (float*)(wsp + STATE_BYTES);
    float* xpring = (float*)(wsp + STATE_BYTES + (size_t)2 * BB * chunkT * HH * 4);

    // zero persistent state (h/c/pooled); ws is re-poisoned before every call
    hipMemsetAsync(d_ws, 0, STATE_BYTES, stream);

    // pipeline: slot c runs A(c) || B(c-1) || C(c-2)
    const int nslots = nchunks + 2;
    for (int c = 0; c < nslots; ++c) {
        lstm_slot_kernel<<<80, 512, 0, stream>>>(
            x, Wih0, Whh0, bih0, bhh0, Wih1, Whh1, bih1, bhh1,
            h1s, c1s, h2s, c2s, pooled, h1ring, xpring,
            c, chunkT, nchunks);
    }
    head_kernel<<<BB, 128, 0, stream>>>(pooled, fcW1, fcb1, fcW2, fcb2, out);
}